// Round 14
// baseline (414.824 us; speedup 1.0000x reference)
//
#include <hip/hip_runtime.h>
#include <hip/hip_bf16.h>
#include <math.h>

// Problem constants
constexpr int BATCH   = 4096;
constexpr int NCLS    = 10;
constexpr int NHID    = 4096;   // OUT_HIDDEN
constexpr int PREV    = 512;    // NHID / ARG_IN
constexpr int NTYPES  = 16;
constexpr int CG      = 32;     // cells per type per row
constexpr float LN_EPS = 1e-5f;

typedef __attribute__((ext_vector_type(8))) short short8;   // 8 bf16 (4 VGPRs)
typedef __attribute__((ext_vector_type(4))) float f32x4;    // MFMA accumulator

// ---------------------------------------------------------------------------
// bf16 MFMA GEMM (m97 structure): Cb[M,4096] (bf16) = A @ BT^T + bias
// ---------------------------------------------------------------------------
__global__ __launch_bounds__(256)
void gemm_bf16_kernel(const __hip_bfloat16* __restrict__ A,   // M x K
                      const __hip_bfloat16* __restrict__ BT,  // 4096 x K
                      const float* __restrict__ bias,
                      __hip_bfloat16* __restrict__ Cb,        // M x 4096 bf16
                      int K) {
  __shared__ __hip_bfloat16 As[128 * 32];
  __shared__ __hip_bfloat16 Bs[128 * 32];
  const int tid  = threadIdx.x;
  const int wid  = tid >> 6;
  const int lane = tid & 63;
  const int row0 = blockIdx.y * 128;
  const int col0 = blockIdx.x * 128;
  const int wrow = (wid >> 1) * 64;
  const int wcol = (wid & 1) * 64;

  f32x4 acc[4][4] = {};

  const int sr = wid * 32;
  const int lr = lane >> 2;
  const int lc = (lane & 3) * 8;

  const int fr = lane & 15;
  const int lq = lane >> 4;
  const int fo = lq * 8;

  for (int k0 = 0; k0 < K; k0 += 32) {
    const __hip_bfloat16* ga0 = A  + (size_t)(row0 + sr +      lr) * K + k0 + lc;
    const __hip_bfloat16* ga1 = A  + (size_t)(row0 + sr + 16 + lr) * K + k0 + lc;
    const __hip_bfloat16* gb0 = BT + (size_t)(col0 + sr +      lr) * K + k0 + lc;
    const __hip_bfloat16* gb1 = BT + (size_t)(col0 + sr + 16 + lr) * K + k0 + lc;
    __builtin_amdgcn_global_load_lds((const __attribute__((address_space(1))) void*)ga0,
                                     (__attribute__((address_space(3))) void*)&As[(sr     ) * 32], 16, 0, 0);
    __builtin_amdgcn_global_load_lds((const __attribute__((address_space(1))) void*)ga1,
                                     (__attribute__((address_space(3))) void*)&As[(sr + 16) * 32], 16, 0, 0);
    __builtin_amdgcn_global_load_lds((const __attribute__((address_space(1))) void*)gb0,
                                     (__attribute__((address_space(3))) void*)&Bs[(sr     ) * 32], 16, 0, 0);
    __builtin_amdgcn_global_load_lds((const __attribute__((address_space(1))) void*)gb1,
                                     (__attribute__((address_space(3))) void*)&Bs[(sr + 16) * 32], 16, 0, 0);
    __syncthreads();

    short8 af[4], bfr[4];
    #pragma unroll
    for (int i = 0; i < 4; ++i)
      af[i] = *reinterpret_cast<const short8*>(&As[(wrow + i * 16 + fr) * 32 + fo]);
    #pragma unroll
    for (int j = 0; j < 4; ++j)
      bfr[j] = *reinterpret_cast<const short8*>(&Bs[(wcol + j * 16 + fr) * 32 + fo]);

    #pragma unroll
    for (int i = 0; i < 4; ++i)
      #pragma unroll
      for (int j = 0; j < 4; ++j)
        acc[i][j] = __builtin_amdgcn_mfma_f32_16x16x32_bf16(af[i], bfr[j], acc[i][j], 0, 0, 0);
    __syncthreads();
  }

  #pragma unroll
  for (int j = 0; j < 4; ++j) {
    const int cc = col0 + wcol + j * 16 + fr;
    const float bv = bias[cc];
    #pragma unroll
    for (int i = 0; i < 4; ++i) {
      const int rr = row0 + wrow + i * 16 + lq * 4;
      #pragma unroll
      for (int r = 0; r < 4; ++r)
        Cb[(size_t)(rr + r) * NHID + cc] = __float2bfloat16(acc[i][j][r] + bv);
    }
  }
}

// ---------------------------------------------------------------------------
// LN stats over bf16 activations: one wave per row. stats[row] = (mu, rs)
// ---------------------------------------------------------------------------
__global__ __launch_bounds__(256)
void ln_stats_bf16_kernel(const __hip_bfloat16* __restrict__ Xb, float2* __restrict__ stats) {
  const int lane = threadIdx.x & 63;
  const int row  = blockIdx.x * 4 + (threadIdx.x >> 6);
  const __hip_bfloat16* p = Xb + (size_t)row * NHID;
  float s = 0.f, ss = 0.f;
  #pragma unroll
  for (int i = 0; i < 8; ++i) {
    union { short8 v; unsigned short u[8]; } b;
    b.v = *reinterpret_cast<const short8*>(&p[i * 512 + lane * 8]);
    #pragma unroll
    for (int j = 0; j < 8; ++j) {
      const float f = __uint_as_float(((unsigned)b.u[j]) << 16);
      s += f;
      ss = fmaf(f, f, ss);
    }
  }
  #pragma unroll
  for (int off = 32; off; off >>= 1) { s += __shfl_xor(s, off); ss += __shfl_xor(ss, off); }
  if (lane == 0) {
    const float mu = s * (1.f / 4096.f);
    float2 st;
    st.x = mu;
    st.y = rsqrtf(ss * (1.f / 4096.f) - mu * mu + LN_EPS);
    stats[row] = st;
  }
}

// ---------------------------------------------------------------------------
// fp32 -> bf16 conversion (vectorized)
// ---------------------------------------------------------------------------
__global__ __launch_bounds__(256)
void cvt_bf16_kernel(const float* __restrict__ in, __hip_bfloat16* __restrict__ out, int n) {
  const int i = (blockIdx.x * 256 + threadIdx.x) * 4;
  if (i >= n) return;
  const float4 v = *reinterpret_cast<const float4*>(&in[i]);
  __hip_bfloat16 t[4];
  t[0] = __float2bfloat16(v.x); t[1] = __float2bfloat16(v.y);
  t[2] = __float2bfloat16(v.z); t[3] = __float2bfloat16(v.w);
  *reinterpret_cast<ushort4*>(&out[i]) = *reinterpret_cast<const ushort4*>(t);
}

// ---------------------------------------------------------------------------
// W (K x N fp32) -> WT (N x K bf16) transpose+convert, 64x64 LDS tiles
// ---------------------------------------------------------------------------
__global__ __launch_bounds__(256)
void transpose_cvt_kernel(const float* __restrict__ W, __hip_bfloat16* __restrict__ WT,
                          int K, int N) {
  __shared__ __hip_bfloat16 tile[64][65];
  const int tid = threadIdx.x;
  const int kt = blockIdx.y * 64, nt = blockIdx.x * 64;
  const int cn = tid & 63;
  for (int r = tid >> 6; r < 64; r += 4)
    tile[cn][r] = __float2bfloat16(W[(size_t)(kt + r) * N + nt + cn]);
  __syncthreads();
  for (int r = tid >> 6; r < 64; r += 4)
    WT[(size_t)(nt + r) * K + kt + cn] = tile[r][cn];
}

// ---------------------------------------------------------------------------
// Weight prep for inner MLP (per type t = blockIdx.x)
// ---------------------------------------------------------------------------
__global__ __launch_bounds__(256)
void prep_weights_kernel(const float* __restrict__ W2, const float* __restrict__ W1,
                         __hip_bfloat16* __restrict__ W2Tb,
                         __hip_bfloat16* __restrict__ W1b,
                         float* __restrict__ swsum) {
  const int t = blockIdx.x;
  for (int idx = threadIdx.x; idx < 64 * 64; idx += 256) {
    const int n = idx >> 6, h = idx & 63;
    W2Tb[t * 4096 + n * 64 + h] = __float2bfloat16(W2[t * 4096 + h * 64 + n]);
  }
  for (int idx = threadIdx.x; idx < 512; idx += 256) {
    const int n = idx >> 3, k = idx & 7;
    W1b[t * 512 + idx] = __float2bfloat16(W1[t * 512 + k * 64 + n]);
  }
  if (threadIdx.x < 64) {
    float s = 0.f;
    #pragma unroll
    for (int k = 0; k < 8; ++k) s += W1[t * 512 + k * 64 + threadIdx.x];
    swsum[t * 64 + threadIdx.x] = s;
  }
}

// ---------------------------------------------------------------------------
// Inner grouped MLPs — round-13 base + DEEP PREFETCH (distance 3):
// four named z/stats register sets rotate A->B->C->D; loads for row n+3 are
// issued before BODY(n), so ~3 BODY-latencies (>2000 cyc) cover any L2/HBM
// miss (depth-1 ping-pong only covered ~600 cyc of the 200-900 cyc latency).
// All register indices compile-time (rule #20). H1s dbuf kept (null/harmless).
// ---------------------------------------------------------------------------
__global__ __launch_bounds__(256, 3)
void inner_type_kernel(const __hip_bfloat16* __restrict__ Xb,  // (B,4096) bf16 pre-LN
                       const float2* __restrict__ stats,       // (B,) mu, rs
                       float* __restrict__ out,                // (B,512) or null
                       __hip_bfloat16* __restrict__ outb,
                       const __hip_bfloat16* __restrict__ W2Tb,
                       const __hip_bfloat16* __restrict__ W1b,
                       const float* __restrict__ swsum,
                       const float* __restrict__ b1,
                       const float* __restrict__ b2,
                       const float* __restrict__ W3, const float* __restrict__ b3) {
  __shared__ __hip_bfloat16 H1s[2 * 128 * 64];   // 32 KB, 2 x 16 KB ping-pong
  const int tid  = threadIdx.x;
  const int lane = tid & 63;
  const int wvid = tid >> 6;
  const int t    = blockIdx.y;
  const int r0   = blockIdx.x * 32;

  const int fc  = lane & 15;
  const int fq  = lane >> 4;
  const bool ld = (fq == 0);

  const __hip_bfloat16* zcol = Xb + t * 256 + fc * 8;

#define LOAD_Z(zf0, zf1, itv)                                                  \
  if (ld) {                                                                    \
    const __hip_bfloat16* zb_ = zcol + (size_t)(r0 + (itv) * 4 + wvid) * NHID; \
    zf0 = *reinterpret_cast<const short8*>(zb_);                               \
    zf1 = *reinterpret_cast<const short8*>(zb_ + 128);                         \
  }

  short8 zfA0 = {}, zfA1 = {}, zfB0 = {}, zfB1 = {};
  short8 zfC0 = {}, zfC1 = {}, zfD0 = {}, zfD1 = {};
  float2 stA, stB, stC, stD;
  // issue rows 0..2 before the weight startup (T14: loads hide under startup)
  LOAD_Z(zfA0, zfA1, 0);  stA = stats[r0 + 0 * 4 + wvid];
  LOAD_Z(zfB0, zfB1, 1);  stB = stats[r0 + 1 * 4 + wvid];
  LOAD_Z(zfC0, zfC1, 2);  stC = stats[r0 + 2 * 4 + wvid];

  // ---- startup: weights loaded ONCE ----
  short8 w1frag[4];
  #pragma unroll
  for (int nf = 0; nf < 4; ++nf) {
    short8 v = {};
    if (ld) v = *reinterpret_cast<const short8*>(&W1b[(size_t)t * 512 + (nf * 16 + fc) * 8]);
    w1frag[nf] = v;
  }

  short8 bfrag[4][2];
  #pragma unroll
  for (int cf = 0; cf < 4; ++cf)
    #pragma unroll
    for (int ks = 0; ks < 2; ++ks)
      bfrag[cf][ks] = *reinterpret_cast<const short8*>(
          &W2Tb[(size_t)t * 4096 + (cf * 16 + fc) * 64 + ks * 32 + fq * 8]);

  float4 b1q[4], swq[4];
  #pragma unroll
  for (int nf = 0; nf < 4; ++nf) {
    b1q[nf] = *reinterpret_cast<const float4*>(&b1[t * 64 + nf * 16 + fq * 4]);
    swq[nf] = *reinterpret_cast<const float4*>(&swsum[t * 64 + nf * 16 + fq * 4]);
  }

  float b2v[4], w3v[4];
  #pragma unroll
  for (int cf = 0; cf < 4; ++cf) {
    b2v[cf] = b2[t * 64 + cf * 16 + fc];
    w3v[cf] = W3[t * 64 + cf * 16 + fc];
  }
  const float yb = b3[t];

#define BODY(zf0, zf1, stv, itv, buf)                                          \
  {                                                                            \
    __hip_bfloat16* const H1b_ = H1s + (buf) * (128 * 64);                     \
    const int row_ = r0 + (itv) * 4 + wvid;                                    \
    const float rs_ = stv.y;                                                   \
    const float c1_ = -stv.x * rs_;                                            \
    /* L1: 8 MFMA, pC[nf][ci] = W1^T x z (n rows, cells cols) */               \
    f32x4 pC[4][2] = {};                                                       \
    _Pragma("unroll")                                                          \
    for (int nf = 0; nf < 4; ++nf) {                                           \
      pC[nf][0] = __builtin_amdgcn_mfma_f32_16x16x32_bf16(w1frag[nf], zf0, pC[nf][0], 0, 0, 0); \
      pC[nf][1] = __builtin_amdgcn_mfma_f32_16x16x32_bf16(w1frag[nf], zf1, pC[nf][1], 0, 0, 0); \
    }                                                                          \
    /* epilogue-L1: h = relu(rs*pC + b1 + c1*sw), b64 writes (4 contig n) */   \
    _Pragma("unroll")                                                          \
    for (int nf = 0; nf < 4; ++nf) {                                           \
      const float bx = fmaf(c1_, swq[nf].x, b1q[nf].x);                        \
      const float by = fmaf(c1_, swq[nf].y, b1q[nf].y);                        \
      const float bz = fmaf(c1_, swq[nf].z, b1q[nf].z);                        \
      const float bw = fmaf(c1_, swq[nf].w, b1q[nf].w);                        \
      _Pragma("unroll")                                                        \
      for (int ci = 0; ci < 2; ++ci) {                                         \
        union { uint2 u; __hip_bfloat16 e[4]; } pk_;                           \
        pk_.e[0] = __float2bfloat16(fmaxf(fmaf(rs_, pC[nf][ci][0], bx), 0.f)); \
        pk_.e[1] = __float2bfloat16(fmaxf(fmaf(rs_, pC[nf][ci][1], by), 0.f)); \
        pk_.e[2] = __float2bfloat16(fmaxf(fmaf(rs_, pC[nf][ci][2], bz), 0.f)); \
        pk_.e[3] = __float2bfloat16(fmaxf(fmaf(rs_, pC[nf][ci][3], bw), 0.f)); \
        const int cell_ = wvid * 32 + ci * 16 + fc;                            \
        const int boff_ = cell_ * 128 + ((nf * 32 + fq * 8) ^ ((cell_ & 7) << 4)); \
        *reinterpret_cast<uint2*>((char*)H1b_ + boff_) = pk_.u;                \
      }                                                                        \
    }                                                                          \
    /* L2 MFMA: wave-private rows of H1b */                                    \
    f32x4 acc[2][4] = {};                                                      \
    _Pragma("unroll")                                                          \
    for (int ks = 0; ks < 2; ++ks) {                                           \
      short8 a0_, a1_;                                                         \
      {                                                                        \
        const int hrow_ = wvid * 32 + fc;                                      \
        a0_ = *reinterpret_cast<const short8*>(                                \
            &H1b_[hrow_ * 64 + ((ks * 32 + fq * 8) ^ ((hrow_ & 7) << 3))]);    \
      }                                                                        \
      {                                                                        \
        const int hrow_ = wvid * 32 + 16 + fc;                                 \
        a1_ = *reinterpret_cast<const short8*>(                                \
            &H1b_[hrow_ * 64 + ((ks * 32 + fq * 8) ^ ((hrow_ & 7) << 3))]);    \
      }                                                                        \
      _Pragma("unroll")                                                        \
      for (int cf = 0; cf < 4; ++cf) {                                         \
        acc[0][cf] = __builtin_amdgcn_mfma_f32_16x16x32_bf16(a0_, bfrag[cf][ks], acc[0][cf], 0, 0, 0); \
        acc[1][cf] = __builtin_amdgcn_mfma_f32_16x16x32_bf16(a1_, bfrag[cf][ks], acc[1][cf], 0, 0, 0); \
      }                                                                        \
    }                                                                          \
    /* L3 epilogue */                                                          \
    float p[2][4];                                                             \
    _Pragma("unroll")                                                          \
    for (int rf = 0; rf < 2; ++rf)                                             \
      _Pragma("unroll")                                                        \
      for (int r = 0; r < 4; ++r) {                                            \
        float s_ = 0.f;                                                        \
        _Pragma("unroll")                                                      \
        for (int cf = 0; cf < 4; ++cf)                                         \
          s_ = fmaf(fmaxf(acc[rf][cf][r] + b2v[cf], 0.f), w3v[cf], s_);        \
        s_ += __shfl_xor(s_, 1);                                               \
        s_ += __shfl_xor(s_, 2);                                               \
        s_ += __shfl_xor(s_, 4);                                               \
        s_ += __shfl_xor(s_, 8);                                               \
        p[rf][r] = s_;                                                         \
      }                                                                        \
    if (fc == 0) {                                                             \
      _Pragma("unroll")                                                        \
      for (int rf = 0; rf < 2; ++rf)                                           \
        _Pragma("unroll")                                                      \
        for (int r = 0; r < 4; ++r) {                                          \
          const int c_ = rf * 16 + fq * 4 + r;                                 \
          const float y_ = p[rf][r] + yb;                                      \
          const size_t oidx_ = (size_t)row_ * PREV + t * CG + c_;              \
          if (out) out[oidx_] = y_;                                            \
          outb[oidx_] = __float2bfloat16(y_);                                  \
        }                                                                      \
    }                                                                          \
  }

  #pragma unroll 1
  for (int it4 = 0; it4 < 8; it4 += 4) {
    // issue loads 3 BODIES ahead of use
    if (it4 + 3 < 8) { LOAD_Z(zfD0, zfD1, it4 + 3); stD = stats[r0 + (it4 + 3) * 4 + wvid]; }
    BODY(zfA0, zfA1, stA, it4 + 0, 0);
    if (it4 + 4 < 8) { LOAD_Z(zfA0, zfA1, it4 + 4); stA = stats[r0 + (it4 + 4) * 4 + wvid]; }
    BODY(zfB0, zfB1, stB, it4 + 1, 1);
    if (it4 + 5 < 8) { LOAD_Z(zfB0, zfB1, it4 + 5); stB = stats[r0 + (it4 + 5) * 4 + wvid]; }
    BODY(zfC0, zfC1, stC, it4 + 2, 0);
    if (it4 + 6 < 8) { LOAD_Z(zfC0, zfC1, it4 + 6); stC = stats[r0 + (it4 + 6) * 4 + wvid]; }
    BODY(zfD0, zfD1, stD, it4 + 3, 1);
  }
#undef LOAD_Z
#undef BODY
}

// ---------------------------------------------------------------------------
// Head: logits = Y @ Wfc + bfc ; per-row NLL into rowloss (one wave per row)
// ---------------------------------------------------------------------------
__global__ __launch_bounds__(64)
void head_kernel(const float* __restrict__ Y, const float* __restrict__ Wfc,
                 const float* __restrict__ bfc, const int* __restrict__ labels,
                 float* __restrict__ logits, float* __restrict__ rowloss) {
  const int b = blockIdx.x;
  const int lane = threadIdx.x;
  const float* yr = Y + (size_t)b * PREV;
  float acc[NCLS] = {};
  for (int k = lane; k < PREV; k += 64) {
    const float yv = yr[k];
    #pragma unroll
    for (int cI = 0; cI < NCLS; ++cI) acc[cI] = fmaf(yv, Wfc[k * NCLS + cI], acc[cI]);
  }
  #pragma unroll
  for (int cI = 0; cI < NCLS; ++cI) {
    #pragma unroll
    for (int off = 32; off; off >>= 1) acc[cI] += __shfl_down(acc[cI], off);
  }
  if (lane == 0) {
    float l[NCLS];
    float m = -1e30f;
    #pragma unroll
    for (int cI = 0; cI < NCLS; ++cI) { l[cI] = acc[cI] + bfc[cI]; m = fmaxf(m, l[cI]); }
    float se = 0.f;
    #pragma unroll
    for (int cI = 0; cI < NCLS; ++cI) se += __expf(l[cI] - m);
    const float lse = m + __logf(se);
    #pragma unroll
    for (int cI = 0; cI < NCLS; ++cI) logits[(size_t)b * NCLS + cI] = l[cI];
    const int lab = labels[b];
    float picked = 0.f;
    #pragma unroll
    for (int cI = 0; cI < NCLS; ++cI) picked += (cI == lab) ? l[cI] : 0.f;
    rowloss[b] = lse - picked;
  }
}

// ---------------------------------------------------------------------------
// Deterministic loss reduction (single block)
// ---------------------------------------------------------------------------
__global__ __launch_bounds__(256)
void loss_reduce_kernel(const float* __restrict__ rowloss, float* __restrict__ loss_out) {
  float s = 0.f;
  for (int i = threadIdx.x; i < BATCH; i += 256) s += rowloss[i];
  #pragma unroll
  for (int off = 32; off; off >>= 1) s += __shfl_down(s, off);
  __shared__ float sb[4];
  if ((threadIdx.x & 63) == 0) sb[threadIdx.x >> 6] = s;
  __syncthreads();
  if (threadIdx.x == 0) loss_out[0] = (sb[0] + sb[1] + sb[2] + sb[3]) * (1.f / BATCH);
}

// ---------------------------------------------------------------------------
extern "C" void kernel_launch(void* const* d_in, const int* in_sizes, int n_in,
                              void* d_out, int out_size, void* d_ws, size_t ws_size,
                              hipStream_t stream) {
  const float* x      = (const float*)d_in[0];
  const int*   labels = (const int*)  d_in[1];
  const float* Wout0  = (const float*)d_in[2];
  const float* bout0  = (const float*)d_in[3];
  const float* Wout1  = (const float*)d_in[4];
  const float* bout1  = (const float*)d_in[5];
  const float* Wout2  = (const float*)d_in[6];
  const float* bout2  = (const float*)d_in[7];
  const float* W1     = (const float*)d_in[8];
  const float* b1     = (const float*)d_in[9];
  const float* W2     = (const float*)d_in[10];
  const float* b2     = (const float*)d_in[11];
  const float* W3     = (const float*)d_in[12];
  const float* b3     = (const float*)d_in[13];
  const float* Wfc    = (const float*)d_in[14];
  const float* bfc    = (const float*)d_in[15];

  char* ws = (char*)d_ws;
  __hip_bfloat16* Abf     = (__hip_bfloat16*)(ws);                      // 32 MB bf16 4096x4096
  float*          Ybuf    = (float*)(ws + ((size_t)32 << 20));          //  8 MB fp32 4096x512
  __hip_bfloat16* Ybf     = (__hip_bfloat16*)(ws + ((size_t)40 << 20)); //  4 MB bf16 4096x512
  __hip_bfloat16* xbf     = (__hip_bfloat16*)(ws + ((size_t)44 << 20)); //  8 MB bf16 4096x1024
  __hip_bfloat16* WT0     = (__hip_bfloat16*)(ws + ((size_t)52 << 20)); //  8 MB bf16 4096x1024
  __hip_bfloat16* WT1     = (__hip_bfloat16*)(ws + ((size_t)60 << 20)); //  4 MB bf16 4096x512
  __hip_bfloat16* WT2     = (__hip_bfloat16*)(ws + ((size_t)64 << 20)); //  4 MB bf16 4096x512
  __hip_bfloat16* W2Tb    = (__hip_bfloat16*)(ws + ((size_t)68 << 20)); // 128 KB
  __hip_bfloat16* W1b     = (__hip_bfloat16*)(ws + ((size_t)68 << 20) + (128 << 10)); // 16 KB
  float*          swsum   = (float*)(ws + ((size_t)68 << 20) + (192 << 10));          //  4 KB
  float2*         stats   = (float2*)(ws + ((size_t)70 << 20));         // 32 KB
  float*          rowloss = (float*)(ws + ((size_t)71 << 20));          // 16 KB

  float* logits = (float*)d_out;
  float* loss   = logits + (size_t)BATCH * NCLS;

  // per-launch weight/input conversions (deterministic, cheap)
  cvt_bf16_kernel<<<dim3(BATCH * 1024 / 4 / 256), dim3(256), 0, stream>>>(x, xbf, BATCH * 1024);
  transpose_cvt_kernel<<<dim3(NHID / 64, 1024 / 64), dim3(256), 0, stream>>>(Wout0, WT0, 1024, NHID);
  transpose_cvt_kernel<<<dim3(NHID / 64, PREV / 64), dim3(256), 0, stream>>>(Wout1, WT1, PREV, NHID);
  transpose_cvt_kernel<<<dim3(NHID / 64, PREV / 64), dim3(256), 0, stream>>>(Wout2, WT2, PREV, NHID);
  prep_weights_kernel<<<dim3(NTYPES), dim3(256), 0, stream>>>(W2, W1, W2Tb, W1b, swsum);

  const dim3 ggrid(NHID / 128, BATCH / 128), gblk(256);
  const dim3 sgrid(BATCH / 4), sblk(256);
  const dim3 igrid(BATCH / 32, NTYPES), iblk(256);

  // layer 0
  gemm_bf16_kernel<<<ggrid, gblk, 0, stream>>>(xbf, WT0, bout0, Abf, 1024);
  ln_stats_bf16_kernel<<<sgrid, sblk, 0, stream>>>(Abf, stats);
  inner_type_kernel<<<igrid, iblk, 0, stream>>>(Abf, stats, nullptr, Ybf, W2Tb, W1b, swsum, b1, b2, W3, b3);
  // layer 1
  gemm_bf16_kernel<<<ggrid, gblk, 0, stream>>>(Ybf, WT1, bout1, Abf, PREV);
  ln_stats_bf16_kernel<<<sgrid, sblk, 0, stream>>>(Abf, stats);
  inner_type_kernel<<<igrid, iblk, 0, stream>>>(Abf, stats, nullptr, Ybf, W2Tb, W1b, swsum, b1, b2, W3, b3);
  // layer 2
  gemm_bf16_kernel<<<ggrid, gblk, 0, stream>>>(Ybf, WT2, bout2, Abf, PREV);
  ln_stats_bf16_kernel<<<sgrid, sblk, 0, stream>>>(Abf, stats);
  inner_type_kernel<<<igrid, iblk, 0, stream>>>(Abf, stats, Ybuf, Ybf, W2Tb, W1b, swsum, b1, b2, W3, b3);

  // head + loss
  head_kernel<<<dim3(BATCH), dim3(64), 0, stream>>>(Ybuf, Wfc, bfc, labels, logits, rowloss);
  loss_reduce_kernel<<<dim3(1), dim3(256), 0, stream>>>(rowloss, loss);
}

// Round 15
// 331.920 us; speedup vs baseline: 1.2498x; 1.2498x over previous
//
#include <hip/hip_runtime.h>
#include <hip/hip_bf16.h>
#include <math.h>

// Problem constants
constexpr int BATCH   = 4096;
constexpr int NCLS    = 10;
constexpr int NHID    = 4096;   // OUT_HIDDEN
constexpr int PREV    = 512;    // NHID / ARG_IN
constexpr int NTYPES  = 16;
constexpr int CG      = 32;     // cells per type per row
constexpr float LN_EPS = 1e-5f;

typedef __attribute__((ext_vector_type(8))) short short8;   // 8 bf16 (4 VGPRs)
typedef __attribute__((ext_vector_type(4))) float f32x4;    // MFMA accumulator

// ---------------------------------------------------------------------------
// bf16 MFMA GEMM (m97 structure): Cb[M,4096] (bf16) = A @ BT^T + bias
// ---------------------------------------------------------------------------
__global__ __launch_bounds__(256)
void gemm_bf16_kernel(const __hip_bfloat16* __restrict__ A,   // M x K
                      const __hip_bfloat16* __restrict__ BT,  // 4096 x K
                      const float* __restrict__ bias,
                      __hip_bfloat16* __restrict__ Cb,        // M x 4096 bf16
                      int K) {
  __shared__ __hip_bfloat16 As[128 * 32];
  __shared__ __hip_bfloat16 Bs[128 * 32];
  const int tid  = threadIdx.x;
  const int wid  = tid >> 6;
  const int lane = tid & 63;
  const int row0 = blockIdx.y * 128;
  const int col0 = blockIdx.x * 128;
  const int wrow = (wid >> 1) * 64;
  const int wcol = (wid & 1) * 64;

  f32x4 acc[4][4] = {};

  const int sr = wid * 32;
  const int lr = lane >> 2;
  const int lc = (lane & 3) * 8;

  const int fr = lane & 15;
  const int lq = lane >> 4;
  const int fo = lq * 8;

  for (int k0 = 0; k0 < K; k0 += 32) {
    const __hip_bfloat16* ga0 = A  + (size_t)(row0 + sr +      lr) * K + k0 + lc;
    const __hip_bfloat16* ga1 = A  + (size_t)(row0 + sr + 16 + lr) * K + k0 + lc;
    const __hip_bfloat16* gb0 = BT + (size_t)(col0 + sr +      lr) * K + k0 + lc;
    const __hip_bfloat16* gb1 = BT + (size_t)(col0 + sr + 16 + lr) * K + k0 + lc;
    __builtin_amdgcn_global_load_lds((const __attribute__((address_space(1))) void*)ga0,
                                     (__attribute__((address_space(3))) void*)&As[(sr     ) * 32], 16, 0, 0);
    __builtin_amdgcn_global_load_lds((const __attribute__((address_space(1))) void*)ga1,
                                     (__attribute__((address_space(3))) void*)&As[(sr + 16) * 32], 16, 0, 0);
    __builtin_amdgcn_global_load_lds((const __attribute__((address_space(1))) void*)gb0,
                                     (__attribute__((address_space(3))) void*)&Bs[(sr     ) * 32], 16, 0, 0);
    __builtin_amdgcn_global_load_lds((const __attribute__((address_space(1))) void*)gb1,
                                     (__attribute__((address_space(3))) void*)&Bs[(sr + 16) * 32], 16, 0, 0);
    __syncthreads();

    short8 af[4], bfr[4];
    #pragma unroll
    for (int i = 0; i < 4; ++i)
      af[i] = *reinterpret_cast<const short8*>(&As[(wrow + i * 16 + fr) * 32 + fo]);
    #pragma unroll
    for (int j = 0; j < 4; ++j)
      bfr[j] = *reinterpret_cast<const short8*>(&Bs[(wcol + j * 16 + fr) * 32 + fo]);

    #pragma unroll
    for (int i = 0; i < 4; ++i)
      #pragma unroll
      for (int j = 0; j < 4; ++j)
        acc[i][j] = __builtin_amdgcn_mfma_f32_16x16x32_bf16(af[i], bfr[j], acc[i][j], 0, 0, 0);
    __syncthreads();
  }

  #pragma unroll
  for (int j = 0; j < 4; ++j) {
    const int cc = col0 + wcol + j * 16 + fr;
    const float bv = bias[cc];
    #pragma unroll
    for (int i = 0; i < 4; ++i) {
      const int rr = row0 + wrow + i * 16 + lq * 4;
      #pragma unroll
      for (int r = 0; r < 4; ++r)
        Cb[(size_t)(rr + r) * NHID + cc] = __float2bfloat16(acc[i][j][r] + bv);
    }
  }
}

// ---------------------------------------------------------------------------
// LN stats over bf16 activations: one wave per row. stats[row] = (mu, rs)
// ---------------------------------------------------------------------------
__global__ __launch_bounds__(256)
void ln_stats_bf16_kernel(const __hip_bfloat16* __restrict__ Xb, float2* __restrict__ stats) {
  const int lane = threadIdx.x & 63;
  const int row  = blockIdx.x * 4 + (threadIdx.x >> 6);
  const __hip_bfloat16* p = Xb + (size_t)row * NHID;
  float s = 0.f, ss = 0.f;
  #pragma unroll
  for (int i = 0; i < 8; ++i) {
    union { short8 v; unsigned short u[8]; } b;
    b.v = *reinterpret_cast<const short8*>(&p[i * 512 + lane * 8]);
    #pragma unroll
    for (int j = 0; j < 8; ++j) {
      const float f = __uint_as_float(((unsigned)b.u[j]) << 16);
      s += f;
      ss = fmaf(f, f, ss);
    }
  }
  #pragma unroll
  for (int off = 32; off; off >>= 1) { s += __shfl_xor(s, off); ss += __shfl_xor(ss, off); }
  if (lane == 0) {
    const float mu = s * (1.f / 4096.f);
    float2 st;
    st.x = mu;
    st.y = rsqrtf(ss * (1.f / 4096.f) - mu * mu + LN_EPS);
    stats[row] = st;
  }
}

// ---------------------------------------------------------------------------
// Fused prep: one launch replaces {cvt x, transpose WT0/WT1/WT2, prep W1/W2}.
// blockIdx.x ranges:
//   [0,2048)            : x (4096x1024 fp32) -> xbf bf16, 8 elems/thread
//   [2048,3072)         : Wout0 (1024x4096) -> WT0 (4096x1024), 64x64 tiles
//   [3072,3584)         : Wout1 (512x4096)  -> WT1 (4096x512)
//   [3584,4096)         : Wout2 (512x4096)  -> WT2 (4096x512)
//   [4096,4112)         : per-type W2 transpose + W1 transpose + swsum
// ---------------------------------------------------------------------------
__global__ __launch_bounds__(256)
void fused_prep_kernel(const float* __restrict__ x, __hip_bfloat16* __restrict__ xbf,
                       const float* __restrict__ Wout0, __hip_bfloat16* __restrict__ WT0,
                       const float* __restrict__ Wout1, __hip_bfloat16* __restrict__ WT1,
                       const float* __restrict__ Wout2, __hip_bfloat16* __restrict__ WT2,
                       const float* __restrict__ W2, const float* __restrict__ W1,
                       __hip_bfloat16* __restrict__ W2Tb, __hip_bfloat16* __restrict__ W1b,
                       float* __restrict__ swsum) {
  __shared__ __hip_bfloat16 tile[64][65];
  const int bid = blockIdx.x;
  const int tid = threadIdx.x;

  if (bid < 2048) {
    // ---- x -> bf16, 8 floats per thread
    const int i = (bid * 256 + tid) * 8;
    const float4 v0 = *reinterpret_cast<const float4*>(&x[i]);
    const float4 v1 = *reinterpret_cast<const float4*>(&x[i + 4]);
    __hip_bfloat16 t[8];
    t[0] = __float2bfloat16(v0.x); t[1] = __float2bfloat16(v0.y);
    t[2] = __float2bfloat16(v0.z); t[3] = __float2bfloat16(v0.w);
    t[4] = __float2bfloat16(v1.x); t[5] = __float2bfloat16(v1.y);
    t[6] = __float2bfloat16(v1.z); t[7] = __float2bfloat16(v1.w);
    *reinterpret_cast<short8*>(&xbf[i]) = *reinterpret_cast<const short8*>(t);
    return;
  }

  const float* W = nullptr;
  __hip_bfloat16* WT = nullptr;
  int K = 0, tb = 0;
  if (bid < 3072)      { W = Wout0; WT = WT0; K = 1024; tb = bid - 2048; }
  else if (bid < 3584) { W = Wout1; WT = WT1; K = 512;  tb = bid - 3072; }
  else if (bid < 4096) { W = Wout2; WT = WT2; K = 512;  tb = bid - 3584; }

  if (W) {
    // ---- W (K x 4096) -> WT (4096 x K) transpose+convert, 64x64 tile
    const int nt = (tb & 63) * 64;          // col tile in N=4096
    const int kt = (tb >> 6) * 64;          // row tile in K
    const int cn = tid & 63;
    for (int r = tid >> 6; r < 64; r += 4)
      tile[cn][r] = __float2bfloat16(W[(size_t)(kt + r) * NHID + nt + cn]);
    __syncthreads();
    for (int r = tid >> 6; r < 64; r += 4)
      WT[(size_t)(nt + r) * K + kt + cn] = tile[r][cn];
    return;
  }

  // ---- per-type inner-MLP weight prep
  const int t = bid - 4096;
  for (int idx = tid; idx < 64 * 64; idx += 256) {
    const int n = idx >> 6, h = idx & 63;
    W2Tb[t * 4096 + n * 64 + h] = __float2bfloat16(W2[t * 4096 + h * 64 + n]);
  }
  for (int idx = tid; idx < 512; idx += 256) {
    const int n = idx >> 3, k = idx & 7;
    W1b[t * 512 + idx] = __float2bfloat16(W1[t * 512 + k * 64 + n]);
  }
  if (tid < 64) {
    float s = 0.f;
    #pragma unroll
    for (int k = 0; k < 8; ++k) s += W1[t * 512 + k * 64 + tid];
    swsum[t * 64 + tid] = s;
  }
}

// ---------------------------------------------------------------------------
// Inner grouped MLPs — round-13 config (best measured: 64 us/dispatch).
// 4 waves/block, one TYPE per block, 32 rows, depth-1 ping-pong prefetch,
// H1s double buffer. Deeper prefetch (r14) spilled to scratch: keep depth 1.
// ---------------------------------------------------------------------------
__global__ __launch_bounds__(256, 3)
void inner_type_kernel(const __hip_bfloat16* __restrict__ Xb,  // (B,4096) bf16 pre-LN
                       const float2* __restrict__ stats,       // (B,) mu, rs
                       float* __restrict__ out,                // (B,512) or null
                       __hip_bfloat16* __restrict__ outb,
                       const __hip_bfloat16* __restrict__ W2Tb,
                       const __hip_bfloat16* __restrict__ W1b,
                       const float* __restrict__ swsum,
                       const float* __restrict__ b1,
                       const float* __restrict__ b2,
                       const float* __restrict__ W3, const float* __restrict__ b3) {
  __shared__ __hip_bfloat16 H1s[2 * 128 * 64];   // 32 KB, 2 x 16 KB ping-pong
  const int tid  = threadIdx.x;
  const int lane = tid & 63;
  const int wvid = tid >> 6;
  const int t    = blockIdx.y;
  const int r0   = blockIdx.x * 32;

  const int fc  = lane & 15;
  const int fq  = lane >> 4;
  const bool ld = (fq == 0);

  const __hip_bfloat16* zcol = Xb + t * 256 + fc * 8;

#define LOAD_Z(zf0, zf1, itv)                                                  \
  if (ld) {                                                                    \
    const __hip_bfloat16* zb_ = zcol + (size_t)(r0 + (itv) * 4 + wvid) * NHID; \
    zf0 = *reinterpret_cast<const short8*>(zb_);                               \
    zf1 = *reinterpret_cast<const short8*>(zb_ + 128);                         \
  }

  short8 zfA0 = {}, zfA1 = {}, zfB0 = {}, zfB1 = {};
  float2 stA, stB;
  LOAD_Z(zfA0, zfA1, 0);
  stA = stats[r0 + wvid];

  // ---- startup: weights loaded ONCE ----
  short8 w1frag[4];
  #pragma unroll
  for (int nf = 0; nf < 4; ++nf) {
    short8 v = {};
    if (ld) v = *reinterpret_cast<const short8*>(&W1b[(size_t)t * 512 + (nf * 16 + fc) * 8]);
    w1frag[nf] = v;
  }

  short8 bfrag[4][2];
  #pragma unroll
  for (int cf = 0; cf < 4; ++cf)
    #pragma unroll
    for (int ks = 0; ks < 2; ++ks)
      bfrag[cf][ks] = *reinterpret_cast<const short8*>(
          &W2Tb[(size_t)t * 4096 + (cf * 16 + fc) * 64 + ks * 32 + fq * 8]);

  float4 b1q[4], swq[4];
  #pragma unroll
  for (int nf = 0; nf < 4; ++nf) {
    b1q[nf] = *reinterpret_cast<const float4*>(&b1[t * 64 + nf * 16 + fq * 4]);
    swq[nf] = *reinterpret_cast<const float4*>(&swsum[t * 64 + nf * 16 + fq * 4]);
  }

  float b2v[4], w3v[4];
  #pragma unroll
  for (int cf = 0; cf < 4; ++cf) {
    b2v[cf] = b2[t * 64 + cf * 16 + fc];
    w3v[cf] = W3[t * 64 + cf * 16 + fc];
  }
  const float yb = b3[t];

#define BODY(zf0, zf1, stv, itv)                                               \
  {                                                                            \
    __hip_bfloat16* const H1b_ = H1s + ((itv) & 1) * (128 * 64);               \
    const int row_ = r0 + (itv) * 4 + wvid;                                    \
    const float rs_ = stv.y;                                                   \
    const float c1_ = -stv.x * rs_;                                            \
    /* L1: 8 MFMA, pC[nf][ci] = W1^T x z (n rows, cells cols) */               \
    f32x4 pC[4][2] = {};                                                       \
    _Pragma("unroll")                                                          \
    for (int nf = 0; nf < 4; ++nf) {                                           \
      pC[nf][0] = __builtin_amdgcn_mfma_f32_16x16x32_bf16(w1frag[nf], zf0, pC[nf][0], 0, 0, 0); \
      pC[nf][1] = __builtin_amdgcn_mfma_f32_16x16x32_bf16(w1frag[nf], zf1, pC[nf][1], 0, 0, 0); \
    }                                                                          \
    /* epilogue-L1: h = relu(rs*pC + b1 + c1*sw), b64 writes (4 contig n) */   \
    _Pragma("unroll")                                                          \
    for (int nf = 0; nf < 4; ++nf) {                                           \
      const float bx = fmaf(c1_, swq[nf].x, b1q[nf].x);                        \
      const float by = fmaf(c1_, swq[nf].y, b1q[nf].y);                        \
      const float bz = fmaf(c1_, swq[nf].z, b1q[nf].z);                        \
      const float bw = fmaf(c1_, swq[nf].w, b1q[nf].w);                        \
      _Pragma("unroll")                                                        \
      for (int ci = 0; ci < 2; ++ci) {                                         \
        union { uint2 u; __hip_bfloat16 e[4]; } pk_;                           \
        pk_.e[0] = __float2bfloat16(fmaxf(fmaf(rs_, pC[nf][ci][0], bx), 0.f)); \
        pk_.e[1] = __float2bfloat16(fmaxf(fmaf(rs_, pC[nf][ci][1], by), 0.f)); \
        pk_.e[2] = __float2bfloat16(fmaxf(fmaf(rs_, pC[nf][ci][2], bz), 0.f)); \
        pk_.e[3] = __float2bfloat16(fmaxf(fmaf(rs_, pC[nf][ci][3], bw), 0.f)); \
        const int cell_ = wvid * 32 + ci * 16 + fc;                            \
        const int boff_ = cell_ * 128 + ((nf * 32 + fq * 8) ^ ((cell_ & 7) << 4)); \
        *reinterpret_cast<uint2*>((char*)H1b_ + boff_) = pk_.u;                \
      }                                                                        \
    }                                                                          \
    /* L2 MFMA: wave-private rows of H1b */                                    \
    f32x4 acc[2][4] = {};                                                      \
    _Pragma("unroll")                                                          \
    for (int ks = 0; ks < 2; ++ks) {                                           \
      short8 a0_, a1_;                                                         \
      {                                                                        \
        const int hrow_ = wvid * 32 + fc;                                      \
        a0_ = *reinterpret_cast<const short8*>(                                \
            &H1b_[hrow_ * 64 + ((ks * 32 + fq * 8) ^ ((hrow_ & 7) << 3))]);    \
      }                                                                        \
      {                                                                        \
        const int hrow_ = wvid * 32 + 16 + fc;                                 \
        a1_ = *reinterpret_cast<const short8*>(                                \
            &H1b_[hrow_ * 64 + ((ks * 32 + fq * 8) ^ ((hrow_ & 7) << 3))]);    \
      }                                                                        \
      _Pragma("unroll")                                                        \
      for (int cf = 0; cf < 4; ++cf) {                                         \
        acc[0][cf] = __builtin_amdgcn_mfma_f32_16x16x32_bf16(a0_, bfrag[cf][ks], acc[0][cf], 0, 0, 0); \
        acc[1][cf] = __builtin_amdgcn_mfma_f32_16x16x32_bf16(a1_, bfrag[cf][ks], acc[1][cf], 0, 0, 0); \
      }                                                                        \
    }                                                                          \
    /* L3 epilogue */                                                          \
    float p[2][4];                                                             \
    _Pragma("unroll")                                                          \
    for (int rf = 0; rf < 2; ++rf)                                             \
      _Pragma("unroll")                                                        \
      for (int r = 0; r < 4; ++r) {                                            \
        float s_ = 0.f;                                                        \
        _Pragma("unroll")                                                      \
        for (int cf = 0; cf < 4; ++cf)                                         \
          s_ = fmaf(fmaxf(acc[rf][cf][r] + b2v[cf], 0.f), w3v[cf], s_);        \
        s_ += __shfl_xor(s_, 1);                                               \
        s_ += __shfl_xor(s_, 2);                                               \
        s_ += __shfl_xor(s_, 4);                                               \
        s_ += __shfl_xor(s_, 8);                                               \
        p[rf][r] = s_;                                                         \
      }                                                                        \
    if (fc == 0) {                                                             \
      _Pragma("unroll")                                                        \
      for (int rf = 0; rf < 2; ++rf)                                           \
        _Pragma("unroll")                                                      \
        for (int r = 0; r < 4; ++r) {                                          \
          const int c_ = rf * 16 + fq * 4 + r;                                 \
          const float y_ = p[rf][r] + yb;                                      \
          const size_t oidx_ = (size_t)row_ * PREV + t * CG + c_;              \
          if (out) out[oidx_] = y_;                                            \
          outb[oidx_] = __float2bfloat16(y_);                                  \
        }                                                                      \
    }                                                                          \
  }

  #pragma unroll 1
  for (int it2 = 0; it2 < 4; ++it2) {
    const int itA = it2 * 2;
    LOAD_Z(zfB0, zfB1, itA + 1);
    stB = stats[r0 + (itA + 1) * 4 + wvid];
    BODY(zfA0, zfA1, stA, itA);
    if (it2 < 3) {
      LOAD_Z(zfA0, zfA1, itA + 2);
      stA = stats[r0 + (itA + 2) * 4 + wvid];
    }
    BODY(zfB0, zfB1, stB, itA + 1);
  }
#undef LOAD_Z
#undef BODY
}

// ---------------------------------------------------------------------------
// Head: logits = Y @ Wfc + bfc ; per-row NLL into rowloss (one wave per row)
// ---------------------------------------------------------------------------
__global__ __launch_bounds__(64)
void head_kernel(const float* __restrict__ Y, const float* __restrict__ Wfc,
                 const float* __restrict__ bfc, const int* __restrict__ labels,
                 float* __restrict__ logits, float* __restrict__ rowloss) {
  const int b = blockIdx.x;
  const int lane = threadIdx.x;
  const float* yr = Y + (size_t)b * PREV;
  float acc[NCLS] = {};
  for (int k = lane; k < PREV; k += 64) {
    const float yv = yr[k];
    #pragma unroll
    for (int cI = 0; cI < NCLS; ++cI) acc[cI] = fmaf(yv, Wfc[k * NCLS + cI], acc[cI]);
  }
  #pragma unroll
  for (int cI = 0; cI < NCLS; ++cI) {
    #pragma unroll
    for (int off = 32; off; off >>= 1) acc[cI] += __shfl_down(acc[cI], off);
  }
  if (lane == 0) {
    float l[NCLS];
    float m = -1e30f;
    #pragma unroll
    for (int cI = 0; cI < NCLS; ++cI) { l[cI] = acc[cI] + bfc[cI]; m = fmaxf(m, l[cI]); }
    float se = 0.f;
    #pragma unroll
    for (int cI = 0; cI < NCLS; ++cI) se += __expf(l[cI] - m);
    const float lse = m + __logf(se);
    #pragma unroll
    for (int cI = 0; cI < NCLS; ++cI) logits[(size_t)b * NCLS + cI] = l[cI];
    const int lab = labels[b];
    float picked = 0.f;
    #pragma unroll
    for (int cI = 0; cI < NCLS; ++cI) picked += (cI == lab) ? l[cI] : 0.f;
    rowloss[b] = lse - picked;
  }
}

// ---------------------------------------------------------------------------
// Deterministic loss reduction (single block)
// ---------------------------------------------------------------------------
__global__ __launch_bounds__(256)
void loss_reduce_kernel(const float* __restrict__ rowloss, float* __restrict__ loss_out) {
  float s = 0.f;
  for (int i = threadIdx.x; i < BATCH; i += 256) s += rowloss[i];
  #pragma unroll
  for (int off = 32; off; off >>= 1) s += __shfl_down(s, off);
  __shared__ float sb[4];
  if ((threadIdx.x & 63) == 0) sb[threadIdx.x >> 6] = s;
  __syncthreads();
  if (threadIdx.x == 0) loss_out[0] = (sb[0] + sb[1] + sb[2] + sb[3]) * (1.f / BATCH);
}

// ---------------------------------------------------------------------------
extern "C" void kernel_launch(void* const* d_in, const int* in_sizes, int n_in,
                              void* d_out, int out_size, void* d_ws, size_t ws_size,
                              hipStream_t stream) {
  const float* x      = (const float*)d_in[0];
  const int*   labels = (const int*)  d_in[1];
  const float* Wout0  = (const float*)d_in[2];
  const float* bout0  = (const float*)d_in[3];
  const float* Wout1  = (const float*)d_in[4];
  const float* bout1  = (const float*)d_in[5];
  const float* Wout2  = (const float*)d_in[6];
  const float* bout2  = (const float*)d_in[7];
  const float* W1     = (const float*)d_in[8];
  const float* b1     = (const float*)d_in[9];
  const float* W2     = (const float*)d_in[10];
  const float* b2     = (const float*)d_in[11];
  const float* W3     = (const float*)d_in[12];
  const float* b3     = (const float*)d_in[13];
  const float* Wfc    = (const float*)d_in[14];
  const float* bfc    = (const float*)d_in[15];

  char* ws = (char*)d_ws;
  __hip_bfloat16* Abf     = (__hip_bfloat16*)(ws);                      // 32 MB bf16 4096x4096
  float*          Ybuf    = (float*)(ws + ((size_t)32 << 20));          //  8 MB fp32 4096x512
  __hip_bfloat16* Ybf     = (__hip_bfloat16*)(ws + ((size_t)40 << 20)); //  4 MB bf16 4096x512
  __hip_bfloat16* xbf     = (__hip_bfloat16*)(ws + ((size_t)44 << 20)); //  8 MB bf16 4096x1024
  __hip_bfloat16* WT0     = (__hip_bfloat16*)(ws + ((size_t)52 << 20)); //  8 MB bf16 4096x1024
  __hip_bfloat16* WT1     = (__hip_bfloat16*)(ws + ((size_t)60 << 20)); //  4 MB bf16 4096x512
  __hip_bfloat16* WT2     = (__hip_bfloat16*)(ws + ((size_t)64 << 20)); //  4 MB bf16 4096x512
  __hip_bfloat16* W2Tb    = (__hip_bfloat16*)(ws + ((size_t)68 << 20)); // 128 KB
  __hip_bfloat16* W1b     = (__hip_bfloat16*)(ws + ((size_t)68 << 20) + (128 << 10)); // 16 KB
  float*          swsum   = (float*)(ws + ((size_t)68 << 20) + (192 << 10));          //  4 KB
  float2*         stats   = (float2*)(ws + ((size_t)70 << 20));         // 32 KB
  float*          rowloss = (float*)(ws + ((size_t)71 << 20));          // 16 KB

  float* logits = (float*)d_out;
  float* loss   = logits + (size_t)BATCH * NCLS;

  // single fused prep launch (replaces 5 kernels)
  fused_prep_kernel<<<dim3(4112), dim3(256), 0, stream>>>(
      x, xbf, Wout0, WT0, Wout1, WT1, Wout2, WT2, W2, W1, W2Tb, W1b, swsum);

  const dim3 ggrid(NHID / 128, BATCH / 128), gblk(256);
  const dim3 sgrid(BATCH / 4), sblk(256);
  const dim3 igrid(BATCH / 32, NTYPES), iblk(256);

  // layer 0
  gemm_bf16_kernel<<<ggrid, gblk, 0, stream>>>(xbf, WT0, bout0, Abf, 1024);
  ln_stats_bf16_kernel<<<sgrid, sblk, 0, stream>>>(Abf, stats);
  inner_type_kernel<<<igrid, iblk, 0, stream>>>(Abf, stats, nullptr, Ybf, W2Tb, W1b, swsum, b1, b2, W3, b3);
  // layer 1
  gemm_bf16_kernel<<<ggrid, gblk, 0, stream>>>(Ybf, WT1, bout1, Abf, PREV);
  ln_stats_bf16_kernel<<<sgrid, sblk, 0, stream>>>(Abf, stats);
  inner_type_kernel<<<igrid, iblk, 0, stream>>>(Abf, stats, nullptr, Ybf, W2Tb, W1b, swsum, b1, b2, W3, b3);
  // layer 2
  gemm_bf16_kernel<<<ggrid, gblk, 0, stream>>>(Ybf, WT2, bout2, Abf, PREV);
  ln_stats_bf16_kernel<<<sgrid, sblk, 0, stream>>>(Abf, stats);
  inner_type_kernel<<<igrid, iblk, 0, stream>>>(Abf, stats, Ybuf, Ybf, W2Tb, W1b, swsum, b1, b2, W3, b3);

  // head + loss
  head_kernel<<<dim3(BATCH), dim3(64), 0, stream>>>(Ybuf, Wfc, bfc, labels, logits, rowloss);
  loss_reduce_kernel<<<dim3(1), dim3(256), 0, stream>>>(rowloss, loss);
}

// Round 16
// 331.389 us; speedup vs baseline: 1.2518x; 1.0016x over previous
//
#include <hip/hip_runtime.h>
#include <hip/hip_bf16.h>
#include <math.h>

// Problem constants
constexpr int BATCH   = 4096;
constexpr int NCLS    = 10;
constexpr int NHID    = 4096;   // OUT_HIDDEN
constexpr int PREV    = 512;    // NHID / ARG_IN
constexpr int NTYPES  = 16;
constexpr int CG      = 32;     // cells per type per row
constexpr float LN_EPS = 1e-5f;

typedef __attribute__((ext_vector_type(8))) short short8;   // 8 bf16 (4 VGPRs)
typedef __attribute__((ext_vector_type(4))) float f32x4;    // MFMA accumulator

// ---------------------------------------------------------------------------
// bf16 MFMA GEMM (m97 structure): Cb[M,4096] (bf16) = A @ BT^T + bias
// XCD-aware col-block swizzle (T1): grid.x=32, 8 XCDs, XCD = flat%8 = hx%8
// (grid.x * y ≡ 0 mod 8). Remap lx=(hx%8)*4+hx/8 gives each XCD a contiguous
// 512-col B-slice (1-2 MB, L2-resident across ALL row stripes) instead of
// scattered columns spanning the whole 4-8 MB B matrix.
// ---------------------------------------------------------------------------
__global__ __launch_bounds__(256)
void gemm_bf16_kernel(const __hip_bfloat16* __restrict__ A,   // M x K
                      const __hip_bfloat16* __restrict__ BT,  // 4096 x K
                      const float* __restrict__ bias,
                      __hip_bfloat16* __restrict__ Cb,        // M x 4096 bf16
                      int K) {
  __shared__ __hip_bfloat16 As[128 * 32];
  __shared__ __hip_bfloat16 Bs[128 * 32];
  const int tid  = threadIdx.x;
  const int wid  = tid >> 6;
  const int lane = tid & 63;
  const int hx   = blockIdx.x;                    // 0..31
  const int lx   = (hx & 7) * 4 + (hx >> 3);      // bijective XCD-chunked remap
  const int row0 = blockIdx.y * 128;
  const int col0 = lx * 128;
  const int wrow = (wid >> 1) * 64;
  const int wcol = (wid & 1) * 64;

  f32x4 acc[4][4] = {};

  const int sr = wid * 32;
  const int lr = lane >> 2;
  const int lc = (lane & 3) * 8;

  const int fr = lane & 15;
  const int lq = lane >> 4;
  const int fo = lq * 8;

  for (int k0 = 0; k0 < K; k0 += 32) {
    const __hip_bfloat16* ga0 = A  + (size_t)(row0 + sr +      lr) * K + k0 + lc;
    const __hip_bfloat16* ga1 = A  + (size_t)(row0 + sr + 16 + lr) * K + k0 + lc;
    const __hip_bfloat16* gb0 = BT + (size_t)(col0 + sr +      lr) * K + k0 + lc;
    const __hip_bfloat16* gb1 = BT + (size_t)(col0 + sr + 16 + lr) * K + k0 + lc;
    __builtin_amdgcn_global_load_lds((const __attribute__((address_space(1))) void*)ga0,
                                     (__attribute__((address_space(3))) void*)&As[(sr     ) * 32], 16, 0, 0);
    __builtin_amdgcn_global_load_lds((const __attribute__((address_space(1))) void*)ga1,
                                     (__attribute__((address_space(3))) void*)&As[(sr + 16) * 32], 16, 0, 0);
    __builtin_amdgcn_global_load_lds((const __attribute__((address_space(1))) void*)gb0,
                                     (__attribute__((address_space(3))) void*)&Bs[(sr     ) * 32], 16, 0, 0);
    __builtin_amdgcn_global_load_lds((const __attribute__((address_space(1))) void*)gb1,
                                     (__attribute__((address_space(3))) void*)&Bs[(sr + 16) * 32], 16, 0, 0);
    __syncthreads();

    short8 af[4], bfr[4];
    #pragma unroll
    for (int i = 0; i < 4; ++i)
      af[i] = *reinterpret_cast<const short8*>(&As[(wrow + i * 16 + fr) * 32 + fo]);
    #pragma unroll
    for (int j = 0; j < 4; ++j)
      bfr[j] = *reinterpret_cast<const short8*>(&Bs[(wcol + j * 16 + fr) * 32 + fo]);

    #pragma unroll
    for (int i = 0; i < 4; ++i)
      #pragma unroll
      for (int j = 0; j < 4; ++j)
        acc[i][j] = __builtin_amdgcn_mfma_f32_16x16x32_bf16(af[i], bfr[j], acc[i][j], 0, 0, 0);
    __syncthreads();
  }

  #pragma unroll
  for (int j = 0; j < 4; ++j) {
    const int cc = col0 + wcol + j * 16 + fr;
    const float bv = bias[cc];
    #pragma unroll
    for (int i = 0; i < 4; ++i) {
      const int rr = row0 + wrow + i * 16 + lq * 4;
      #pragma unroll
      for (int r = 0; r < 4; ++r)
        Cb[(size_t)(rr + r) * NHID + cc] = __float2bfloat16(acc[i][j][r] + bv);
    }
  }
}

// ---------------------------------------------------------------------------
// LN stats over bf16 activations: one wave per row. stats[row] = (mu, rs)
// ---------------------------------------------------------------------------
__global__ __launch_bounds__(256)
void ln_stats_bf16_kernel(const __hip_bfloat16* __restrict__ Xb, float2* __restrict__ stats) {
  const int lane = threadIdx.x & 63;
  const int row  = blockIdx.x * 4 + (threadIdx.x >> 6);
  const __hip_bfloat16* p = Xb + (size_t)row * NHID;
  float s = 0.f, ss = 0.f;
  #pragma unroll
  for (int i = 0; i < 8; ++i) {
    union { short8 v; unsigned short u[8]; } b;
    b.v = *reinterpret_cast<const short8*>(&p[i * 512 + lane * 8]);
    #pragma unroll
    for (int j = 0; j < 8; ++j) {
      const float f = __uint_as_float(((unsigned)b.u[j]) << 16);
      s += f;
      ss = fmaf(f, f, ss);
    }
  }
  #pragma unroll
  for (int off = 32; off; off >>= 1) { s += __shfl_xor(s, off); ss += __shfl_xor(ss, off); }
  if (lane == 0) {
    const float mu = s * (1.f / 4096.f);
    float2 st;
    st.x = mu;
    st.y = rsqrtf(ss * (1.f / 4096.f) - mu * mu + LN_EPS);
    stats[row] = st;
  }
}

// ---------------------------------------------------------------------------
// Fused prep: one launch replaces {cvt x, transpose WT0/WT1/WT2, prep W1/W2}.
// blockIdx.x ranges:
//   [0,2048)            : x (4096x1024 fp32) -> xbf bf16, 8 elems/thread
//   [2048,3072)         : Wout0 (1024x4096) -> WT0 (4096x1024), 64x64 tiles
//   [3072,3584)         : Wout1 (512x4096)  -> WT1 (4096x512)
//   [3584,4096)         : Wout2 (512x4096)  -> WT2 (4096x512)
//   [4096,4112)         : per-type W2 transpose + W1 transpose + swsum
// ---------------------------------------------------------------------------
__global__ __launch_bounds__(256)
void fused_prep_kernel(const float* __restrict__ x, __hip_bfloat16* __restrict__ xbf,
                       const float* __restrict__ Wout0, __hip_bfloat16* __restrict__ WT0,
                       const float* __restrict__ Wout1, __hip_bfloat16* __restrict__ WT1,
                       const float* __restrict__ Wout2, __hip_bfloat16* __restrict__ WT2,
                       const float* __restrict__ W2, const float* __restrict__ W1,
                       __hip_bfloat16* __restrict__ W2Tb, __hip_bfloat16* __restrict__ W1b,
                       float* __restrict__ swsum) {
  __shared__ __hip_bfloat16 tile[64][65];
  const int bid = blockIdx.x;
  const int tid = threadIdx.x;

  if (bid < 2048) {
    const int i = (bid * 256 + tid) * 8;
    const float4 v0 = *reinterpret_cast<const float4*>(&x[i]);
    const float4 v1 = *reinterpret_cast<const float4*>(&x[i + 4]);
    __hip_bfloat16 t[8];
    t[0] = __float2bfloat16(v0.x); t[1] = __float2bfloat16(v0.y);
    t[2] = __float2bfloat16(v0.z); t[3] = __float2bfloat16(v0.w);
    t[4] = __float2bfloat16(v1.x); t[5] = __float2bfloat16(v1.y);
    t[6] = __float2bfloat16(v1.z); t[7] = __float2bfloat16(v1.w);
    *reinterpret_cast<short8*>(&xbf[i]) = *reinterpret_cast<const short8*>(t);
    return;
  }

  const float* W = nullptr;
  __hip_bfloat16* WT = nullptr;
  int K = 0, tb = 0;
  if (bid < 3072)      { W = Wout0; WT = WT0; K = 1024; tb = bid - 2048; }
  else if (bid < 3584) { W = Wout1; WT = WT1; K = 512;  tb = bid - 3072; }
  else if (bid < 4096) { W = Wout2; WT = WT2; K = 512;  tb = bid - 3584; }

  if (W) {
    const int nt = (tb & 63) * 64;          // col tile in N=4096
    const int kt = (tb >> 6) * 64;          // row tile in K
    const int cn = tid & 63;
    for (int r = tid >> 6; r < 64; r += 4)
      tile[cn][r] = __float2bfloat16(W[(size_t)(kt + r) * NHID + nt + cn]);
    __syncthreads();
    for (int r = tid >> 6; r < 64; r += 4)
      WT[(size_t)(nt + r) * K + kt + cn] = tile[r][cn];
    return;
  }

  const int t = bid - 4096;
  for (int idx = tid; idx < 64 * 64; idx += 256) {
    const int n = idx >> 6, h = idx & 63;
    W2Tb[t * 4096 + n * 64 + h] = __float2bfloat16(W2[t * 4096 + h * 64 + n]);
  }
  for (int idx = tid; idx < 512; idx += 256) {
    const int n = idx >> 3, k = idx & 7;
    W1b[t * 512 + idx] = __float2bfloat16(W1[t * 512 + k * 64 + n]);
  }
  if (tid < 64) {
    float s = 0.f;
    #pragma unroll
    for (int k = 0; k < 8; ++k) s += W1[t * 512 + k * 64 + tid];
    swsum[t * 64 + tid] = s;
  }
}

// ---------------------------------------------------------------------------
// Inner grouped MLPs — round-13 config (best measured: 64 us/dispatch).
// 4 waves/block, one TYPE per block, 32 rows, depth-1 ping-pong prefetch,
// H1s double buffer. Deeper prefetch (r14) spilled to scratch: keep depth 1.
// ---------------------------------------------------------------------------
__global__ __launch_bounds__(256, 3)
void inner_type_kernel(const __hip_bfloat16* __restrict__ Xb,  // (B,4096) bf16 pre-LN
                       const float2* __restrict__ stats,       // (B,) mu, rs
                       float* __restrict__ out,                // (B,512) or null
                       __hip_bfloat16* __restrict__ outb,
                       const __hip_bfloat16* __restrict__ W2Tb,
                       const __hip_bfloat16* __restrict__ W1b,
                       const float* __restrict__ swsum,
                       const float* __restrict__ b1,
                       const float* __restrict__ b2,
                       const float* __restrict__ W3, const float* __restrict__ b3) {
  __shared__ __hip_bfloat16 H1s[2 * 128 * 64];   // 32 KB, 2 x 16 KB ping-pong
  const int tid  = threadIdx.x;
  const int lane = tid & 63;
  const int wvid = tid >> 6;
  const int t    = blockIdx.y;
  const int r0   = blockIdx.x * 32;

  const int fc  = lane & 15;
  const int fq  = lane >> 4;
  const bool ld = (fq == 0);

  const __hip_bfloat16* zcol = Xb + t * 256 + fc * 8;

#define LOAD_Z(zf0, zf1, itv)                                                  \
  if (ld) {                                                                    \
    const __hip_bfloat16* zb_ = zcol + (size_t)(r0 + (itv) * 4 + wvid) * NHID; \
    zf0 = *reinterpret_cast<const short8*>(zb_);                               \
    zf1 = *reinterpret_cast<const short8*>(zb_ + 128);                         \
  }

  short8 zfA0 = {}, zfA1 = {}, zfB0 = {}, zfB1 = {};
  float2 stA, stB;
  LOAD_Z(zfA0, zfA1, 0);
  stA = stats[r0 + wvid];

  // ---- startup: weights loaded ONCE ----
  short8 w1frag[4];
  #pragma unroll
  for (int nf = 0; nf < 4; ++nf) {
    short8 v = {};
    if (ld) v = *reinterpret_cast<const short8*>(&W1b[(size_t)t * 512 + (nf * 16 + fc) * 8]);
    w1frag[nf] = v;
  }

  short8 bfrag[4][2];
  #pragma unroll
  for (int cf = 0; cf < 4; ++cf)
    #pragma unroll
    for (int ks = 0; ks < 2; ++ks)
      bfrag[cf][ks] = *reinterpret_cast<const short8*>(
          &W2Tb[(size_t)t * 4096 + (cf * 16 + fc) * 64 + ks * 32 + fq * 8]);

  float4 b1q[4], swq[4];
  #pragma unroll
  for (int nf = 0; nf < 4; ++nf) {
    b1q[nf] = *reinterpret_cast<const float4*>(&b1[t * 64 + nf * 16 + fq * 4]);
    swq[nf] = *reinterpret_cast<const float4*>(&swsum[t * 64 + nf * 16 + fq * 4]);
  }

  float b2v[4], w3v[4];
  #pragma unroll
  for (int cf = 0; cf < 4; ++cf) {
    b2v[cf] = b2[t * 64 + cf * 16 + fc];
    w3v[cf] = W3[t * 64 + cf * 16 + fc];
  }
  const float yb = b3[t];

#define BODY(zf0, zf1, stv, itv)                                               \
  {                                                                            \
    __hip_bfloat16* const H1b_ = H1s + ((itv) & 1) * (128 * 64);               \
    const int row_ = r0 + (itv) * 4 + wvid;                                    \
    const float rs_ = stv.y;                                                   \
    const float c1_ = -stv.x * rs_;                                            \
    /* L1: 8 MFMA, pC[nf][ci] = W1^T x z (n rows, cells cols) */               \
    f32x4 pC[4][2] = {};                                                       \
    _Pragma("unroll")                                                          \
    for (int nf = 0; nf < 4; ++nf) {                                           \
      pC[nf][0] = __builtin_amdgcn_mfma_f32_16x16x32_bf16(w1frag[nf], zf0, pC[nf][0], 0, 0, 0); \
      pC[nf][1] = __builtin_amdgcn_mfma_f32_16x16x32_bf16(w1frag[nf], zf1, pC[nf][1], 0, 0, 0); \
    }                                                                          \
    /* epilogue-L1: h = relu(rs*pC + b1 + c1*sw), b64 writes (4 contig n) */   \
    _Pragma("unroll")                                                          \
    for (int nf = 0; nf < 4; ++nf) {                                           \
      const float bx = fmaf(c1_, swq[nf].x, b1q[nf].x);                        \
      const float by = fmaf(c1_, swq[nf].y, b1q[nf].y);                        \
      const float bz = fmaf(c1_, swq[nf].z, b1q[nf].z);                        \
      const float bw = fmaf(c1_, swq[nf].w, b1q[nf].w);                        \
      _Pragma("unroll")                                                        \
      for (int ci = 0; ci < 2; ++ci) {                                         \
        union { uint2 u; __hip_bfloat16 e[4]; } pk_;                           \
        pk_.e[0] = __float2bfloat16(fmaxf(fmaf(rs_, pC[nf][ci][0], bx), 0.f)); \
        pk_.e[1] = __float2bfloat16(fmaxf(fmaf(rs_, pC[nf][ci][1], by), 0.f)); \
        pk_.e[2] = __float2bfloat16(fmaxf(fmaf(rs_, pC[nf][ci][2], bz), 0.f)); \
        pk_.e[3] = __float2bfloat16(fmaxf(fmaf(rs_, pC[nf][ci][3], bw), 0.f)); \
        const int cell_ = wvid * 32 + ci * 16 + fc;                            \
        const int boff_ = cell_ * 128 + ((nf * 32 + fq * 8) ^ ((cell_ & 7) << 4)); \
        *reinterpret_cast<uint2*>((char*)H1b_ + boff_) = pk_.u;                \
      }                                                                        \
    }                                                                          \
    /* L2 MFMA: wave-private rows of H1b */                                    \
    f32x4 acc[2][4] = {};                                                      \
    _Pragma("unroll")                                                          \
    for (int ks = 0; ks < 2; ++ks) {                                           \
      short8 a0_, a1_;                                                         \
      {                                                                        \
        const int hrow_ = wvid * 32 + fc;                                      \
        a0_ = *reinterpret_cast<const short8*>(                                \
            &H1b_[hrow_ * 64 + ((ks * 32 + fq * 8) ^ ((hrow_ & 7) << 3))]);    \
      }                                                                        \
      {                                                                        \
        const int hrow_ = wvid * 32 + 16 + fc;                                 \
        a1_ = *reinterpret_cast<const short8*>(                                \
            &H1b_[hrow_ * 64 + ((ks * 32 + fq * 8) ^ ((hrow_ & 7) << 3))]);    \
      }                                                                        \
      _Pragma("unroll")                                                        \
      for (int cf = 0; cf < 4; ++cf) {                                         \
        acc[0][cf] = __builtin_amdgcn_mfma_f32_16x16x32_bf16(a0_, bfrag[cf][ks], acc[0][cf], 0, 0, 0); \
        acc[1][cf] = __builtin_amdgcn_mfma_f32_16x16x32_bf16(a1_, bfrag[cf][ks], acc[1][cf], 0, 0, 0); \
      }                                                                        \
    }                                                                          \
    /* L3 epilogue */                                                          \
    float p[2][4];                                                             \
    _Pragma("unroll")                                                          \
    for (int rf = 0; rf < 2; ++rf)                                             \
      _Pragma("unroll")                                                        \
      for (int r = 0; r < 4; ++r) {                                            \
        float s_ = 0.f;                                                        \
        _Pragma("unroll")                                                      \
        for (int cf = 0; cf < 4; ++cf)                                         \
          s_ = fmaf(fmaxf(acc[rf][cf][r] + b2v[cf], 0.f), w3v[cf], s_);        \
        s_ += __shfl_xor(s_, 1);                                               \
        s_ += __shfl_xor(s_, 2);                                               \
        s_ += __shfl_xor(s_, 4);                                               \
        s_ += __shfl_xor(s_, 8);                                               \
        p[rf][r] = s_;                                                         \
      }                                                                        \
    if (fc == 0) {                                                             \
      _Pragma("unroll")                                                        \
      for (int rf = 0; rf < 2; ++rf)                                           \
        _Pragma("unroll")                                                      \
        for (int r = 0; r < 4; ++r) {                                          \
          const int c_ = rf * 16 + fq * 4 + r;                                 \
          const float y_ = p[rf][r] + yb;                                      \
          const size_t oidx_ = (size_t)row_ * PREV + t * CG + c_;              \
          if (out) out[oidx_] = y_;                                            \
          outb[oidx_] = __float2bfloat16(y_);                                  \
        }                                                                      \
    }                                                                          \
  }

  #pragma unroll 1
  for (int it2 = 0; it2 < 4; ++it2) {
    const int itA = it2 * 2;
    LOAD_Z(zfB0, zfB1, itA + 1);
    stB = stats[r0 + (itA + 1) * 4 + wvid];
    BODY(zfA0, zfA1, stA, itA);
    if (it2 < 3) {
      LOAD_Z(zfA0, zfA1, itA + 2);
      stA = stats[r0 + (itA + 2) * 4 + wvid];
    }
    BODY(zfB0, zfB1, stB, itA + 1);
  }
#undef LOAD_Z
#undef BODY
}

// ---------------------------------------------------------------------------
// Head: logits = Y @ Wfc + bfc ; per-row NLL into rowloss (one wave per row)
// ---------------------------------------------------------------------------
__global__ __launch_bounds__(64)
void head_kernel(const float* __restrict__ Y, const float* __restrict__ Wfc,
                 const float* __restrict__ bfc, const int* __restrict__ labels,
                 float* __restrict__ logits, float* __restrict__ rowloss) {
  const int b = blockIdx.x;
  const int lane = threadIdx.x;
  const float* yr = Y + (size_t)b * PREV;
  float acc[NCLS] = {};
  for (int k = lane; k < PREV; k += 64) {
    const float yv = yr[k];
    #pragma unroll
    for (int cI = 0; cI < NCLS; ++cI) acc[cI] = fmaf(yv, Wfc[k * NCLS + cI], acc[cI]);
  }
  #pragma unroll
  for (int cI = 0; cI < NCLS; ++cI) {
    #pragma unroll
    for (int off = 32; off; off >>= 1) acc[cI] += __shfl_down(acc[cI], off);
  }
  if (lane == 0) {
    float l[NCLS];
    float m = -1e30f;
    #pragma unroll
    for (int cI = 0; cI < NCLS; ++cI) { l[cI] = acc[cI] + bfc[cI]; m = fmaxf(m, l[cI]); }
    float se = 0.f;
    #pragma unroll
    for (int cI = 0; cI < NCLS; ++cI) se += __expf(l[cI] - m);
    const float lse = m + __logf(se);
    #pragma unroll
    for (int cI = 0; cI < NCLS; ++cI) logits[(size_t)b * NCLS + cI] = l[cI];
    const int lab = labels[b];
    float picked = 0.f;
    #pragma unroll
    for (int cI = 0; cI < NCLS; ++cI) picked += (cI == lab) ? l[cI] : 0.f;
    rowloss[b] = lse - picked;
  }
}

// ---------------------------------------------------------------------------
// Deterministic loss reduction (single block)
// ---------------------------------------------------------------------------
__global__ __launch_bounds__(256)
void loss_reduce_kernel(const float* __restrict__ rowloss, float* __restrict__ loss_out) {
  float s = 0.f;
  for (int i = threadIdx.x; i < BATCH; i += 256) s += rowloss[i];
  #pragma unroll
  for (int off = 32; off; off >>= 1) s += __shfl_down(s, off);
  __shared__ float sb[4];
  if ((threadIdx.x & 63) == 0) sb[threadIdx.x >> 6] = s;
  __syncthreads();
  if (threadIdx.x == 0) loss_out[0] = (sb[0] + sb[1] + sb[2] + sb[3]) * (1.f / BATCH);
}

// ---------------------------------------------------------------------------
extern "C" void kernel_launch(void* const* d_in, const int* in_sizes, int n_in,
                              void* d_out, int out_size, void* d_ws, size_t ws_size,
                              hipStream_t stream) {
  const float* x      = (const float*)d_in[0];
  const int*   labels = (const int*)  d_in[1];
  const float* Wout0  = (const float*)d_in[2];
  const float* bout0  = (const float*)d_in[3];
  const float* Wout1  = (const float*)d_in[4];
  const float* bout1  = (const float*)d_in[5];
  const float* Wout2  = (const float*)d_in[6];
  const float* bout2  = (const float*)d_in[7];
  const float* W1     = (const float*)d_in[8];
  const float* b1     = (const float*)d_in[9];
  const float* W2     = (const float*)d_in[10];
  const float* b2     = (const float*)d_in[11];
  const float* W3     = (const float*)d_in[12];
  const float* b3     = (const float*)d_in[13];
  const float* Wfc    = (const float*)d_in[14];
  const float* bfc    = (const float*)d_in[15];

  char* ws = (char*)d_ws;
  __hip_bfloat16* Abf     = (__hip_bfloat16*)(ws);                      // 32 MB bf16 4096x4096
  float*          Ybuf    = (float*)(ws + ((size_t)32 << 20));          //  8 MB fp32 4096x512
  __hip_bfloat16* Ybf     = (__hip_bfloat16*)(ws + ((size_t)40 << 20)); //  4 MB bf16 4096x512
  __hip_bfloat16* xbf     = (__hip_bfloat16*)(ws + ((size_t)44 << 20)); //  8 MB bf16 4096x1024
  __hip_bfloat16* WT0     = (__hip_bfloat16*)(ws + ((size_t)52 << 20)); //  8 MB bf16 4096x1024
  __hip_bfloat16* WT1     = (__hip_bfloat16*)(ws + ((size_t)60 << 20)); //  4 MB bf16 4096x512
  __hip_bfloat16* WT2     = (__hip_bfloat16*)(ws + ((size_t)64 << 20)); //  4 MB bf16 4096x512
  __hip_bfloat16* W2Tb    = (__hip_bfloat16*)(ws + ((size_t)68 << 20)); // 128 KB
  __hip_bfloat16* W1b     = (__hip_bfloat16*)(ws + ((size_t)68 << 20) + (128 << 10)); // 16 KB
  float*          swsum   = (float*)(ws + ((size_t)68 << 20) + (192 << 10));          //  4 KB
  float2*         stats   = (float2*)(ws + ((size_t)70 << 20));         // 32 KB
  float*          rowloss = (float*)(ws + ((size_t)71 << 20));          // 16 KB

  float* logits = (float*)d_out;
  float* loss   = logits + (size_t)BATCH * NCLS;

  // single fused prep launch (replaces 5 kernels)
  fused_prep_kernel<<<dim3(4112), dim3(256), 0, stream>>>(
      x, xbf, Wout0, WT0, Wout1, WT1, Wout2, WT2, W2, W1, W2Tb, W1b, swsum);

  const dim3 ggrid(NHID / 128, BATCH / 128), gblk(256);
  const dim3 sgrid(BATCH / 4), sblk(256);
  const dim3 igrid(BATCH / 32, NTYPES), iblk(256);

  // layer 0
  gemm_bf16_kernel<<<ggrid, gblk, 0, stream>>>(xbf, WT0, bout0, Abf, 1024);
  ln_stats_bf16_kernel<<<sgrid, sblk, 0, stream>>>(Abf, stats);
  inner_type_kernel<<<igrid, iblk, 0, stream>>>(Abf, stats, nullptr, Ybf, W2Tb, W1b, swsum, b1, b2, W3, b3);
  // layer 1
  gemm_bf16_kernel<<<ggrid, gblk, 0, stream>>>(Ybf, WT1, bout1, Abf, PREV);
  ln_stats_bf16_kernel<<<sgrid, sblk, 0, stream>>>(Abf, stats);
  inner_type_kernel<<<igrid, iblk, 0, stream>>>(Abf, stats, nullptr, Ybf, W2Tb, W1b, swsum, b1, b2, W3, b3);
  // layer 2
  gemm_bf16_kernel<<<ggrid, gblk, 0, stream>>>(Ybf, WT2, bout2, Abf, PREV);
  ln_stats_bf16_kernel<<<sgrid, sblk, 0, stream>>>(Abf, stats);
  inner_type_kernel<<<igrid, iblk, 0, stream>>>(Abf, stats, Ybuf, Ybf, W2Tb, W1b, swsum, b1, b2, W3, b3);

  // head + loss
  head_kernel<<<dim3(BATCH), dim3(64), 0, stream>>>(Ybuf, Wfc, bfc, labels, logits, rowloss);
  loss_reduce_kernel<<<dim3(1), dim3(256), 0, stream>>>(rowloss, loss);
}